// Round 6
// baseline (97.676 us; speedup 1.0000x reference)
//
#include <hip/hip_runtime.h>
#include <math.h>

// Problem constants: B=8, C=16, N=65536, K_CAND=10, K_TOP=4
#define BB 8
#define CC 16
#define NN 65536
#define KC 10
#define KT 4

#define TPTS 32            // points per block tile
#define BLK  256           // 8 lanes per point x 32 points

// 22 KB LDS per block -> 7 blocks/CU (28 waves/CU) vs round-3's 4 blocks/CU.
// All staging loads are full-128B-line segments; block tiles are 1280B-aligned
// so no cache line is shared across blocks (avoids cross-XCD double-fetch).
__global__ __launch_bounds__(BLK, 7) void swg_kernel(
    const float* __restrict__ orig,   // [B][C][N]
    const float* __restrict__ samp,   // [B][C][N][KC]
    const float* __restrict__ w1,     // [2C]
    const float* __restrict__ w2,     // [2C]
    const float* __restrict__ b2p,    // scalar
    float* __restrict__ out)          // [B][C][N]
{
    __shared__ float4 s4[CC * TPTS * KC / 4];   // 1280 float4 = 20 KB
    __shared__ float  obuf[CC * 33];            // padded rows: bank-conflict-free reads

    const int t   = threadIdx.x;
    const int bid = blockIdx.x;
    const int b   = bid >> 11;                  // (bid*32) / 65536
    const int n0  = (bid & 2047) * TPTS;

    // ---- stage sampled: channel sc, 5 x float4, 4 x 256B segments per instr ----
    {
        const int sc = t >> 4;                  // 0..15
        const int sl = t & 15;
        const float4* g4 = (const float4*)(samp + ((size_t)(b * CC + sc) * NN + n0) * KC);
        float4* l4 = s4 + sc * (TPTS * KC / 4); // 80 float4 per channel
#pragma unroll
        for (int j = 0; j < 5; ++j)
            l4[j * 16 + sl] = g4[j * 16 + sl];
    }
    // ---- stage orig: 128 threads, 8 x 128B full-line segments per wave ----
    if (t < 128) {
        const int oc = t >> 3;                  // 0..15
        const int ol = t & 7;                   // float4 index, 8 per channel
        const float4 x = *(const float4*)(orig + (size_t)(b * CC + oc) * NN + n0 + ol * 4);
        float* dst = obuf + oc * 33 + ol * 4;
        dst[0] = x.x; dst[1] = x.y; dst[2] = x.z; dst[3] = x.w;
    }
    __syncthreads();

    // ---- compute: 8 lanes per point, 2 channels per lane (q, q+8) ----
    const int q = t & 7;
    const int p = t >> 3;                       // 0..31
    const int n = n0 + p;

    const float b2 = b2p[0];
    float ws1[2], wo2[2], ws2[2], o[2];
#pragma unroll
    for (int cc = 0; cc < 2; ++cc) {
        const int c = q + 8 * cc;
        ws1[cc] = w1[CC + c];
        wo2[cc] = w2[c];
        ws2[cc] = w2[CC + c];
        o[cc]   = obuf[c * 33 + p];
    }

    float v[2][KC];
#pragma unroll
    for (int cc = 0; cc < 2; ++cc) {
        const float* base = (const float*)s4 + (q + 8 * cc) * (TPTS * KC) + p * KC;
#pragma unroll
        for (int j = 0; j < 5; ++j) {
            const float2 x = *(const float2*)(base + 2 * j);
            v[cc][2 * j]     = x.x;
            v[cc][2 * j + 1] = x.y;
        }
    }

    // ---- phase 1: selection scores s[k] + dO, butterfly over 8 lanes ----
    float s[KC];
    float dO = o[0] * wo2[0] + o[1] * wo2[1];
#pragma unroll
    for (int k = 0; k < KC; ++k)
        s[k] = v[0][k] * ws1[0] + v[1][k] * ws1[1];
#pragma unroll
    for (int m = 1; m <= 4; m <<= 1) {
        dO += __shfl_xor(dO, m, 64);
#pragma unroll
        for (int k = 0; k < KC; ++k) s[k] += __shfl_xor(s[k], m, 64);
    }

    // ---- phase 2: rank counting -> selection mask (s dies here) ----
    unsigned selmask = 0;
#pragma unroll
    for (int k = 0; k < KC; ++k) {
        int rk = 0;
#pragma unroll
        for (int j = 0; j < KC; ++j) {
            if (j == k) continue;
            const bool beats = (j < k) ? (s[j] >= s[k]) : (s[j] > s[k]);
            rk += beats ? 1 : 0;
        }
        selmask |= (rk < KT) ? (1u << k) : 0u;
    }

    // ---- phase 3: recal dots d2[k], butterfly ----
    float d2[KC];
#pragma unroll
    for (int k = 0; k < KC; ++k)
        d2[k] = v[0][k] * ws2[0] + v[1][k] * ws2[1];
#pragma unroll
    for (int m = 1; m <= 4; m <<= 1) {
#pragma unroll
        for (int k = 0; k < KC; ++k) d2[k] += __shfl_xor(d2[k], m, 64);
    }

    // ---- phase 4: sigmoid weights + weighted sum + store ----
    float sum0 = 0.f, sum1 = 0.f;
#pragma unroll
    for (int k = 0; k < KC; ++k) {
        const float x   = dO + d2[k] + b2;
        const float sig = __builtin_amdgcn_rcpf(1.f + __expf(-x));
        const float wk  = ((selmask >> k) & 1u) ? sig : 0.f;
        sum0 += v[0][k] * wk;
        sum1 += v[1][k] * wk;
    }
    out[(size_t)(b * CC + q)     * NN + n] = o[0] + sum0;
    out[(size_t)(b * CC + q + 8) * NN + n] = o[1] + sum1;
}

extern "C" void kernel_launch(void* const* d_in, const int* in_sizes, int n_in,
                              void* d_out, int out_size, void* d_ws, size_t ws_size,
                              hipStream_t stream) {
    const float* orig = (const float*)d_in[0];
    const float* samp = (const float*)d_in[1];
    const float* w1   = (const float*)d_in[2];
    // d_in[3] = b1 (unused: constant shift over k does not change top-k order)
    const float* w2   = (const float*)d_in[4];
    const float* b2   = (const float*)d_in[5];
    float* out = (float*)d_out;

    const int grid = (BB * NN) / TPTS;   // 16384 blocks
    hipLaunchKernelGGL(swg_kernel, dim3(grid), dim3(BLK), 0, stream,
                       orig, samp, w1, w2, b2, out);
}

// Round 7
// 97.607 us; speedup vs baseline: 1.0007x; 1.0007x over previous
//
#include <hip/hip_runtime.h>
#include <math.h>

// Problem constants: B=8, C=16, N=65536, K_CAND=10, K_TOP=4
#define BB 8
#define CC 16
#define NN 65536
#define KC 10
#define KT 4

#define TPTS 32            // points per block tile
#define BLK  256           // 8 lanes per point x 32 points

// All global access at >=128B-per-channel granularity:
//  - samp staged via float4, 256B per channel per instruction
//  - orig staged via float4 full lines
//  - stores: channel-major mapping -> 128B per channel per instruction
// NOTE: no min-waves clamp (round 6's __launch_bounds__(256,7) forced ~64 VGPR
// and likely spilled; this round lets the allocator breathe).
__global__ __launch_bounds__(BLK) void swg_kernel(
    const float* __restrict__ orig,   // [B][C][N]
    const float* __restrict__ samp,   // [B][C][N][KC]
    const float* __restrict__ w1,     // [2C]
    const float* __restrict__ w2,     // [2C]
    const float* __restrict__ b2p,    // scalar
    float* __restrict__ out)          // [B][C][N]
{
    __shared__ float4 s4[CC * TPTS * KC / 4];   // 1280 float4 = 20 KB
    __shared__ float  obuf[CC * 33];            // padded rows for conflict-free reads

    const int t   = threadIdx.x;
    const int bid = blockIdx.x;
    const int b   = bid >> 11;                  // (bid*32) / 65536
    const int n0  = (bid & 2047) * TPTS;

    // ---- stage sampled: channel sc, 5 x float4, 256B/channel per instr ----
    {
        const int sc = t >> 4;                  // 0..15
        const int sl = t & 15;
        const float4* g4 = (const float4*)(samp + ((size_t)(b * CC + sc) * NN + n0) * KC);
        float4* l4 = s4 + sc * (TPTS * KC / 4); // 80 float4 per channel
#pragma unroll
        for (int j = 0; j < 5; ++j)
            l4[j * 16 + sl] = g4[j * 16 + sl];
    }
    // ---- stage orig: 128 threads, full 128B lines ----
    if (t < 128) {
        const int oc = t >> 3;                  // 0..15
        const int ol = t & 7;                   // float4 index, 8 per channel
        const float4 x = *(const float4*)(orig + (size_t)(b * CC + oc) * NN + n0 + ol * 4);
        float* dst = obuf + oc * 33 + ol * 4;
        dst[0] = x.x; dst[1] = x.y; dst[2] = x.z; dst[3] = x.w;
    }
    __syncthreads();

    // ---- compute: 8 lanes per point, 2 channels per lane (q, q+8) ----
    const int q = t & 7;
    const int p = t >> 3;                       // 0..31
    const int n = n0 + p;

    const float b2 = b2p[0];
    float ws1[2], wo2[2], ws2[2], o[2];
#pragma unroll
    for (int cc = 0; cc < 2; ++cc) {
        const int c = q + 8 * cc;
        ws1[cc] = w1[CC + c];
        wo2[cc] = w2[c];
        ws2[cc] = w2[CC + c];
        o[cc]   = obuf[c * 33 + p];
    }

    float v[2][KC];
#pragma unroll
    for (int cc = 0; cc < 2; ++cc) {
        const float* base = (const float*)s4 + (q + 8 * cc) * (TPTS * KC) + p * KC;
#pragma unroll
        for (int j = 0; j < 5; ++j) {
            const float2 x = *(const float2*)(base + 2 * j);
            v[cc][2 * j]     = x.x;
            v[cc][2 * j + 1] = x.y;
        }
    }

    // ---- phase 1: selection scores s[k] + dO, butterfly over 8 lanes ----
    float s[KC];
    float dO = o[0] * wo2[0] + o[1] * wo2[1];
#pragma unroll
    for (int k = 0; k < KC; ++k)
        s[k] = v[0][k] * ws1[0] + v[1][k] * ws1[1];
#pragma unroll
    for (int m = 1; m <= 4; m <<= 1) {
        dO += __shfl_xor(dO, m, 64);
#pragma unroll
        for (int k = 0; k < KC; ++k) s[k] += __shfl_xor(s[k], m, 64);
    }

    // ---- phase 2: rank counting -> selection mask (s dies here) ----
    unsigned selmask = 0;
#pragma unroll
    for (int k = 0; k < KC; ++k) {
        int rk = 0;
#pragma unroll
        for (int j = 0; j < KC; ++j) {
            if (j == k) continue;
            const bool beats = (j < k) ? (s[j] >= s[k]) : (s[j] > s[k]);
            rk += beats ? 1 : 0;
        }
        selmask |= (rk < KT) ? (1u << k) : 0u;
    }

    // ---- phase 3: recal dots d2[k], butterfly ----
    float d2[KC];
#pragma unroll
    for (int k = 0; k < KC; ++k)
        d2[k] = v[0][k] * ws2[0] + v[1][k] * ws2[1];
#pragma unroll
    for (int m = 1; m <= 4; m <<= 1) {
#pragma unroll
        for (int k = 0; k < KC; ++k) d2[k] += __shfl_xor(d2[k], m, 64);
    }

    // ---- phase 4: sigmoid weights + weighted sum + store (128B/channel) ----
    float sum0 = 0.f, sum1 = 0.f;
#pragma unroll
    for (int k = 0; k < KC; ++k) {
        const float x   = dO + d2[k] + b2;
        const float sig = __builtin_amdgcn_rcpf(1.f + __expf(-x));
        const float wk  = ((selmask >> k) & 1u) ? sig : 0.f;
        sum0 += v[0][k] * wk;
        sum1 += v[1][k] * wk;
    }
    out[(size_t)(b * CC + q)     * NN + n] = o[0] + sum0;
    out[(size_t)(b * CC + q + 8) * NN + n] = o[1] + sum1;
}

extern "C" void kernel_launch(void* const* d_in, const int* in_sizes, int n_in,
                              void* d_out, int out_size, void* d_ws, size_t ws_size,
                              hipStream_t stream) {
    const float* orig = (const float*)d_in[0];
    const float* samp = (const float*)d_in[1];
    const float* w1   = (const float*)d_in[2];
    // d_in[3] = b1 (unused: constant shift over k does not change top-k order)
    const float* w2   = (const float*)d_in[4];
    const float* b2   = (const float*)d_in[5];
    float* out = (float*)d_out;

    const int grid = (BB * NN) / TPTS;   // 16384 blocks
    hipLaunchKernelGGL(swg_kernel, dim3(grid), dim3(BLK), 0, stream,
                       orig, samp, w1, w2, b2, out);
}

// Round 8
// 91.985 us; speedup vs baseline: 1.0619x; 1.0611x over previous
//
#include <hip/hip_runtime.h>
#include <math.h>

// Problem constants: B=8, C=16, N=65536, K_CAND=10, K_TOP=4
#define BB 8
#define CC 16
#define NN 65536
#define KC 10
#define KT 4

#define TPT   16           // points per tile
#define TILES 16           // tiles per block
#define BLK   64           // ONE wave per block -> no barriers, wave-local vmcnt only

typedef __attribute__((address_space(3))) void lds_t;
typedef __attribute__((address_space(1))) void glob_t;

// Single-wave software pipeline: double-buffered 16-point tiles staged via
// global_load_lds; per iter {vmcnt(0) -> issue next tile -> compute current}.
// Each wave keeps ~14 VMEM ops perpetually in flight; 8 blocks/CU (LDS-exact).
__global__ __launch_bounds__(BLK) void swg_kernel(
    const float* __restrict__ orig,   // [B][C][N]
    const float* __restrict__ samp,   // [B][C][N][KC]
    const float* __restrict__ w1,     // [2C]
    const float* __restrict__ w2,     // [2C]
    const float* __restrict__ b2p,    // scalar
    float* __restrict__ out)          // [B][C][N]
{
    __shared__ float4 buf[2][TPT * CC * KC / 4];   // 2 x 640 float4 = 20480 B

    const int l   = threadIdx.x & 63;
    const int bid = blockIdx.x;
    const int T0  = bid * TILES;                   // 4096 tiles per batch; 16|4096
    const int b   = T0 >> 12;

    const float4* sampB4 = (const float4*)samp + (size_t)b * ((size_t)CC * NN * KC / 4);
    const float*  origB  = orig + (size_t)b * CC * NN;
    float*        outB   = out  + (size_t)b * CC * NN;

    // staging decomposition: tile float4 idx i = j*64 + l; channel c = i/40,
    // within-channel float4 r = i%40 (channel-major LDS, linear in load order)
    int goff[10];
#pragma unroll
    for (int j = 0; j < 10; ++j) {
        const int i = j * 64 + l;
        const int c = i / 40;
        const int r = i - c * 40;
        goff[j] = c * (NN * KC / 4) + r;
    }

    const int q = l & 3;               // channel group (4 channels per lane)
    const int p = l >> 2;              // local point 0..15

    float ws1[4], wo2[4], ws2[4];
#pragma unroll
    for (int cc = 0; cc < 4; ++cc) {
        const int c = q * 4 + cc;
        ws1[cc] = w1[CC + c];
        wo2[cc] = w2[c];
        ws2[cc] = w2[CC + c];
    }
    const float b2 = b2p[0];

    // ---- prologue: stage tile 0 + orig(0) ----
    {
        const int toff = (T0 & 4095) * 40;
#pragma unroll
        for (int j = 0; j < 10; ++j)
            __builtin_amdgcn_global_load_lds(
                (const glob_t*)(sampB4 + toff + goff[j]),
                (lds_t*)((char*)&buf[0][0] + j * 1024), 16, 0, 0);
    }
    float o_nx[4];
    {
        const int n = (T0 & 4095) * TPT + p;
#pragma unroll
        for (int cc = 0; cc < 4; ++cc)
            o_nx[cc] = origB[(q * 4 + cc) * NN + n];
    }

    for (int g = 0; g < TILES; ++g) {
        const int T = T0 + g;
        const int n = (T & 4095) * TPT + p;

        // tile g's loads are the oldest outstanding; drain them (wave-local)
        asm volatile("s_waitcnt vmcnt(0)" ::: "memory");
        float o[4];
#pragma unroll
        for (int cc = 0; cc < 4; ++cc) o[cc] = o_nx[cc];

        // ---- issue tile g+1 (flies under compute below) ----
        if (g + 1 < TILES) {
            const int Tn   = T + 1;
            const int toff = (Tn & 4095) * 40;
            char* dst = (char*)&buf[(g + 1) & 1][0];
#pragma unroll
            for (int j = 0; j < 10; ++j)
                __builtin_amdgcn_global_load_lds(
                    (const glob_t*)(sampB4 + toff + goff[j]),
                    (lds_t*)(dst + j * 1024), 16, 0, 0);
            const int nn = (Tn & 4095) * TPT + p;
#pragma unroll
            for (int cc = 0; cc < 4; ++cc)
                o_nx[cc] = origB[(q * 4 + cc) * NN + nn];
        }

        // ---- compute tile g ----
        const float* lf = (const float*)&buf[g & 1][0];
        float v[4][KC];
#pragma unroll
        for (int cc = 0; cc < 4; ++cc) {
            const float* base = lf + (q * 4 + cc) * (TPT * KC) + p * KC;
#pragma unroll
            for (int j = 0; j < 5; ++j) {
                const float2 x = *(const float2*)(base + 2 * j);
                v[cc][2 * j]     = x.x;
                v[cc][2 * j + 1] = x.y;
            }
        }

        float s[KC], d2[KC];
        float dO = 0.f;
#pragma unroll
        for (int k = 0; k < KC; ++k) { s[k] = 0.f; d2[k] = 0.f; }
#pragma unroll
        for (int cc = 0; cc < 4; ++cc) {
            dO += o[cc] * wo2[cc];
#pragma unroll
            for (int k = 0; k < KC; ++k) {
                s[k]  += v[cc][k] * ws1[cc];
                d2[k] += v[cc][k] * ws2[cc];
            }
        }

#pragma unroll
        for (int m = 1; m <= 2; m <<= 1) {
            dO += __shfl_xor(dO, m, 64);
#pragma unroll
            for (int k = 0; k < KC; ++k) {
                s[k]  += __shfl_xor(s[k],  m, 64);
                d2[k] += __shfl_xor(d2[k], m, 64);
            }
        }

        // rank counting -> top-4 set (j<k uses >=: lax.top_k tie-break)
        float sum[4] = {0.f, 0.f, 0.f, 0.f};
#pragma unroll
        for (int k = 0; k < KC; ++k) {
            int rk = 0;
#pragma unroll
            for (int j = 0; j < KC; ++j) {
                if (j == k) continue;
                const bool beats = (j < k) ? (s[j] >= s[k]) : (s[j] > s[k]);
                rk += beats ? 1 : 0;
            }
            const float x   = dO + d2[k] + b2;
            const float sig = __builtin_amdgcn_rcpf(1.f + __expf(-x));
            const float wk  = (rk < KT) ? sig : 0.f;
#pragma unroll
            for (int cc = 0; cc < 4; ++cc) sum[cc] += v[cc][k] * wk;
        }

#pragma unroll
        for (int cc = 0; cc < 4; ++cc)
            outB[(q * 4 + cc) * NN + n] = o[cc] + sum[cc];
    }
}

extern "C" void kernel_launch(void* const* d_in, const int* in_sizes, int n_in,
                              void* d_out, int out_size, void* d_ws, size_t ws_size,
                              hipStream_t stream) {
    const float* orig = (const float*)d_in[0];
    const float* samp = (const float*)d_in[1];
    const float* w1   = (const float*)d_in[2];
    // d_in[3] = b1 (unused: constant shift over k does not change top-k order)
    const float* w2   = (const float*)d_in[4];
    const float* b2   = (const float*)d_in[5];
    float* out = (float*)d_out;

    const int grid = (BB * NN) / (TPT * TILES);   // 2048 blocks = 8/CU exactly
    hipLaunchKernelGGL(swg_kernel, dim3(grid), dim3(BLK), 0, stream,
                       orig, samp, w1, w2, b2, out);
}

// Round 9
// 81.349 us; speedup vs baseline: 1.2007x; 1.1307x over previous
//
#include <hip/hip_runtime.h>
#include <math.h>

// Problem constants: B=8, C=16, N=65536, K_CAND=10, K_TOP=4
#define BB 8
#define CC 16
#define NN 65536
#define KC 10
#define KT 4

#define PTW 16             // points per wave tile (16*40B = 640B/channel = 5 lines, aligned)
#define BLK 128            // 2 independent waves per block
#define WFLT (PTW * CC * KC)   // 2560 floats = 10 KB per wave region

typedef __attribute__((address_space(3))) void lds_t;
typedef __attribute__((address_space(1))) void glob_t;

// Wave-independent: each wave stages its own 16-point tile (line-aligned!) via
// global_load_lds, waits wave-local vmcnt(0), computes, stores. NO barriers.
// 20 KB/block -> 8 blocks/CU = 16 waves/CU (same as R2) but zero phase-locking.
__global__ __launch_bounds__(BLK) void swg_kernel(
    const float* __restrict__ orig,   // [B][C][N]
    const float* __restrict__ samp,   // [B][C][N][KC]
    const float* __restrict__ w1,     // [2C]
    const float* __restrict__ w2,     // [2C]
    const float* __restrict__ b2p,    // scalar
    float* __restrict__ out)          // [B][C][N]
{
    __shared__ float buf[2 * WFLT];   // 20 KB

    const int t   = threadIdx.x;
    const int l   = t & 63;
    const int w   = t >> 6;
    const int bid = blockIdx.x;

    const int b    = bid >> 11;                     // (bid*32) / 65536
    const int nloc = ((bid * 32) & (NN - 1)) + w * PTW;

    const float4* sampB4 = (const float4*)samp + (size_t)b * ((size_t)CC * NN * KC / 4);
    const float*  origB  = orig + (size_t)b * CC * NN;
    float*        outB   = out  + (size_t)b * CC * NN;

    float* ldsw = buf + w * WFLT;

    // ---- stage samp tile: unit i = j*64+l -> channel c=i/40, float4 r=i%40;
    //      LDS linear in load order == channel-major (c*640B + r*16B) ----
    const int toff = nloc * 10 / 4;                 // nloc%16==0 -> exact
#pragma unroll
    for (int j = 0; j < 10; ++j) {
        const int i = j * 64 + l;
        const int c = i / 40;
        const int r = i - c * 40;
        __builtin_amdgcn_global_load_lds(
            (const glob_t*)(sampB4 + (size_t)c * (NN * KC / 4) + toff + r),
            (lds_t*)((char*)ldsw + j * 1024), 16, 0, 0);
    }

    // ---- compute ids: 4 lanes per point, 4 channels per lane ----
    const int q = l & 3;
    const int p = l >> 2;              // 0..15
    const int n = nloc + p;

    // orig direct (64B segments; block's 2 waves cover each 128B line -> L2 exact)
    float o[4];
#pragma unroll
    for (int cc = 0; cc < 4; ++cc)
        o[cc] = origB[(q * 4 + cc) * NN + n];

    float ws1[4], wo2[4], ws2[4];
#pragma unroll
    for (int cc = 0; cc < 4; ++cc) {
        const int c = q * 4 + cc;
        ws1[cc] = w1[CC + c];
        wo2[cc] = w2[c];
        ws2[cc] = w2[CC + c];
    }
    const float b2 = b2p[0];

    // wave-local drain of our staging (and orig) — no s_barrier anywhere
    asm volatile("s_waitcnt vmcnt(0)" ::: "memory");

    // ---- read this lane's 4 channels from LDS ----
    float v[4][KC];
#pragma unroll
    for (int cc = 0; cc < 4; ++cc) {
        const float* base = ldsw + (q * 4 + cc) * (PTW * KC) + p * KC;
#pragma unroll
        for (int j = 0; j < 5; ++j) {
            const float2 x = *(const float2*)(base + 2 * j);
            v[cc][2 * j]     = x.x;
            v[cc][2 * j + 1] = x.y;
        }
    }

    // ---- partial dots ----
    float s[KC], d2[KC];
    float dO = 0.f;
#pragma unroll
    for (int k = 0; k < KC; ++k) { s[k] = 0.f; d2[k] = 0.f; }
#pragma unroll
    for (int cc = 0; cc < 4; ++cc) {
        dO += o[cc] * wo2[cc];
#pragma unroll
        for (int k = 0; k < KC; ++k) {
            s[k]  += v[cc][k] * ws1[cc];
            d2[k] += v[cc][k] * ws2[cc];
        }
    }

    // ---- butterfly over the 4-lane point group ----
#pragma unroll
    for (int m = 1; m <= 2; m <<= 1) {
        dO += __shfl_xor(dO, m, 64);
#pragma unroll
        for (int k = 0; k < KC; ++k) {
            s[k]  += __shfl_xor(s[k],  m, 64);
            d2[k] += __shfl_xor(d2[k], m, 64);
        }
    }

    // ---- rank counting -> top-4 set; sigmoid; weighted sum ----
    float sum[4] = {0.f, 0.f, 0.f, 0.f};
#pragma unroll
    for (int k = 0; k < KC; ++k) {
        int rk = 0;
#pragma unroll
        for (int j = 0; j < KC; ++j) {
            if (j == k) continue;
            const bool beats = (j < k) ? (s[j] >= s[k]) : (s[j] > s[k]);
            rk += beats ? 1 : 0;
        }
        const float x   = dO + d2[k] + b2;
        const float sig = __builtin_amdgcn_rcpf(1.f + __expf(-x));
        const float wk  = (rk < KT) ? sig : 0.f;
#pragma unroll
        for (int cc = 0; cc < 4; ++cc) sum[cc] += v[cc][k] * wk;
    }

    // ---- store (64B segments/channel; 2 waves complete each line) ----
#pragma unroll
    for (int cc = 0; cc < 4; ++cc)
        outB[(q * 4 + cc) * NN + n] = o[cc] + sum[cc];
}

extern "C" void kernel_launch(void* const* d_in, const int* in_sizes, int n_in,
                              void* d_out, int out_size, void* d_ws, size_t ws_size,
                              hipStream_t stream) {
    const float* orig = (const float*)d_in[0];
    const float* samp = (const float*)d_in[1];
    const float* w1   = (const float*)d_in[2];
    // d_in[3] = b1 (unused: constant shift over k does not change top-k order)
    const float* w2   = (const float*)d_in[4];
    const float* b2   = (const float*)d_in[5];
    float* out = (float*)d_out;

    const int grid = (BB * NN) / 32;   // 16384 blocks (32 points per block)
    hipLaunchKernelGGL(swg_kernel, dim3(grid), dim3(BLK), 0, stream,
                       orig, samp, w1, w2, b2, out);
}

// Round 10
// 78.323 us; speedup vs baseline: 1.2471x; 1.0386x over previous
//
#include <hip/hip_runtime.h>
#include <math.h>

// Problem constants: B=8, C=16, N=65536, K_CAND=10, K_TOP=4
#define BB 8
#define CC 16
#define NN 65536
#define KC 10
#define KT 4

#define TPTS 64            // points per block
#define BLK  256           // threads per block (4 lanes per point)

// BEST STRUCTURE (R3, 78.4 us = ~5.1 TB/s on 403 MB):
// Stage sampled_features tile through LDS with fully-coalesced float4 loads,
// then compute with 4 lanes per point (4 channels per lane, register-resident
// v[4][10] reused for the weighted-sum pass). Selection via rank counting,
// sigmoid via hardware rcp. Alternatives tested and beaten: software pipelines
// (R4/R8), wave-private no-barrier tiles (R5/R9), 8-lane mapping (R6/R7).
__global__ __launch_bounds__(BLK) void swg_kernel(
    const float* __restrict__ orig,   // [B][C][N]
    const float* __restrict__ samp,   // [B][C][N][KC]
    const float* __restrict__ w1,     // [2C]
    const float* __restrict__ w2,     // [2C]
    const float* __restrict__ b2p,    // scalar
    float* __restrict__ out)          // [B][C][N]
{
    __shared__ float lds[CC * TPTS * KC];   // 16*64*10 = 10240 floats = 40 KB

    const int t = threadIdx.x;
    const int blk = blockIdx.x;
    const int p0 = blk * TPTS;              // first global point of tile
    const int b  = p0 >> 16;                // same b for whole tile (64 | 65536)
    const int n0 = p0 & (NN - 1);

    // ---- compute-side ids ----
    const int q = t & 3;                    // channel group 0..3
    const int p = t >> 2;                   // local point 0..63
    const int n = n0 + p;

    // ---- issue orig loads early (independent of LDS staging) ----
    float o[4];
#pragma unroll
    for (int cc = 0; cc < 4; ++cc) {
        const int c = q * 4 + cc;
        o[cc] = orig[(size_t)(b * CC + c) * NN + n];
    }

    // ---- stage: thread t loads channel (t>>4), 10 float4 chunks, coalesced ----
    {
        const int sc = t >> 4;              // channel 0..15
        const int sl = t & 15;              // chunk lane 0..15
        const size_t gbase = ((size_t)(b * CC + sc) * NN + n0) * KC;
        const float4* g4 = (const float4*)(samp + gbase);   // n0 % 64 == 0 -> 16B aligned
        float4* l4 = (float4*)(lds + sc * (TPTS * KC));
#pragma unroll
        for (int j = 0; j < 10; ++j)
            l4[j * 16 + sl] = g4[j * 16 + sl];
    }
    __syncthreads();

    const float b2 = b2p[0];

    float ws1[4], wo2[4], ws2[4];
#pragma unroll
    for (int cc = 0; cc < 4; ++cc) {
        const int c = q * 4 + cc;
        ws1[cc] = w1[CC + c];
        wo2[cc] = w2[c];
        ws2[cc] = w2[CC + c];
    }

    float v[4][KC];
#pragma unroll
    for (int cc = 0; cc < 4; ++cc) {
        const int c = q * 4 + cc;
        const float2* lp = (const float2*)(lds + c * (TPTS * KC) + p * KC);
#pragma unroll
        for (int j = 0; j < 5; ++j) {
            const float2 x = lp[j];
            v[cc][2 * j]     = x.x;
            v[cc][2 * j + 1] = x.y;
        }
    }

    // ---- partial dots over this lane's 4 channels ----
    float s[KC], d2[KC];
    float dO = 0.f;
#pragma unroll
    for (int k = 0; k < KC; ++k) { s[k] = 0.f; d2[k] = 0.f; }
#pragma unroll
    for (int cc = 0; cc < 4; ++cc) {
        dO += o[cc] * wo2[cc];
#pragma unroll
        for (int k = 0; k < KC; ++k) {
            s[k]  += v[cc][k] * ws1[cc];   // selection score (sigmoid monotone,
            d2[k] += v[cc][k] * ws2[cc];   //  orig-dot + b1 constant over k)
        }
    }

    // ---- butterfly reduce across the 4-lane point group ----
#pragma unroll
    for (int m = 1; m <= 2; m <<= 1) {
        dO += __shfl_xor(dO, m, 64);
#pragma unroll
        for (int k = 0; k < KC; ++k) {
            s[k]  += __shfl_xor(s[k],  m, 64);
            d2[k] += __shfl_xor(d2[k], m, 64);
        }
    }

    // ---- selection by rank counting: k selected iff rank[k] < 4.
    //      beats(j,k) for j<k uses >=, reproducing lax.top_k's lower-index
    //      tie-break; output depends only on the selected SET. ----
    int rank[KC];
#pragma unroll
    for (int k = 0; k < KC; ++k) rank[k] = 0;
#pragma unroll
    for (int j = 0; j < KC; ++j) {
#pragma unroll
        for (int k = j + 1; k < KC; ++k) {
            const bool jge = s[j] >= s[k];
            rank[k] += jge ? 1 : 0;
            rank[j] += jge ? 0 : 1;
        }
    }

    // ---- recal weights: sigmoid via hw rcp (abs tolerance 0.18 >> rcp err) ----
    float w[KC];
#pragma unroll
    for (int k = 0; k < KC; ++k) {
        const float x = dO + d2[k] + b2;
        const float sig = __builtin_amdgcn_rcpf(1.f + __expf(-x));
        w[k] = (rank[k] < KT) ? sig : 0.f;
    }

    // ---- weighted sum (register-resident features) + residual, store ----
#pragma unroll
    for (int cc = 0; cc < 4; ++cc) {
        float sum = 0.f;
#pragma unroll
        for (int k = 0; k < KC; ++k) sum += v[cc][k] * w[k];
        const int c = q * 4 + cc;
        out[(size_t)(b * CC + c) * NN + n] = o[cc] + sum;
    }
}

extern "C" void kernel_launch(void* const* d_in, const int* in_sizes, int n_in,
                              void* d_out, int out_size, void* d_ws, size_t ws_size,
                              hipStream_t stream) {
    const float* orig = (const float*)d_in[0];
    const float* samp = (const float*)d_in[1];
    const float* w1   = (const float*)d_in[2];
    // d_in[3] = b1 (unused: constant shift over k does not change top-k order)
    const float* w2   = (const float*)d_in[4];
    const float* b2   = (const float*)d_in[5];
    float* out = (float*)d_out;

    const int grid = (BB * NN) / TPTS;   // 8192 blocks
    hipLaunchKernelGGL(swg_kernel, dim3(grid), dim3(BLK), 0, stream,
                       orig, samp, w1, w2, b2, out);
}